// Round 6
// baseline (424.917 us; speedup 1.0000x reference)
//
#include <hip/hip_runtime.h>

#define Bn 128
#define Dd 32
#define Pp 13
#define Ee 16
#define Hh 4
#define HDim 4
#define Ll 416           // Dd*Pp
#define Rr (Bn*Ll)       // 53248 rows

// Broadcast lane i's value to all lanes (v_readlane -> SGPR operand).
__device__ __forceinline__ float lane_bcast(float x, int i) {
    return __uint_as_float(__builtin_amdgcn_readlane(__float_as_uint(x), i));
}

// ---------------------------------------------------------------------------
// Kernel A: fused encoder + QKV. 256 threads / 64 rows per block, 832 blocks.
//  phase1: lane = hidden unit; w1 column in 66 VGPRs; 8 INDEPENDENT fma
//          chains (8 rows at once, 2 passes) -> issue-bound, not dep-bound.
//  phase2a: lane=row; wave w computes enc dims 4w..4w+3 (stride-65/17 LDS).
//  phase2b: lane=row; wave w computes qkv outputs 12w..12w+11, 3 coalesced
//          float4 stores.
// Q pre-scaled by 0.5*log2(e) so attention uses raw exp2.
// ---------------------------------------------------------------------------
__global__ __launch_bounds__(256, 4) void enc_qkv_kernel(
    const float* __restrict__ board, const float* __restrict__ w1,
    const float* __restrict__ b1, const float* __restrict__ w2,
    const float* __restrict__ b2, const float* __restrict__ w_qkv,
    const float* __restrict__ b_qkv,
    float* __restrict__ Q, float* __restrict__ K, float* __restrict__ V)
{
    __shared__ float sh[64 * 65];    // h, stride 65 (conflict-free)
    __shared__ float se[64 * 17];    // enc, stride 17 (conflict-free)

    const int tid  = threadIdx.x;
    const int w    = tid >> 6;       // wave id 0..3
    const int lane = tid & 63;
    const int row0 = blockIdx.x * 64;

    // ---- phase 1: h = relu(feats @ w1 + b1); lane = hidden unit ----
    {
        float wcol[66];
        #pragma unroll
        for (int i = 0; i < 66; ++i) wcol[i] = w1[i * 64 + lane];
        const float bias1 = b1[lane];

        // Coalesced: lane loads element `lane` of each of the wave's 16 rows.
        float fv[16];
        #pragma unroll
        for (int r = 0; r < 16; ++r)
            fv[r] = board[(size_t)(row0 + w * 16 + r) * 64 + lane];

        #pragma unroll
        for (int pass = 0; pass < 2; ++pass) {
            // 8 independent accumulator chains -> VALU issue-bound.
            float a0 = bias1, a1 = bias1, a2 = bias1, a3 = bias1;
            float a4 = bias1, a5 = bias1, a6 = bias1, a7 = bias1;
            const int rb = pass * 8;
            #pragma unroll
            for (int i = 0; i < 64; ++i) {
                a0 = fmaf(lane_bcast(fv[rb + 0], i), wcol[i], a0);
                a1 = fmaf(lane_bcast(fv[rb + 1], i), wcol[i], a1);
                a2 = fmaf(lane_bcast(fv[rb + 2], i), wcol[i], a2);
                a3 = fmaf(lane_bcast(fv[rb + 3], i), wcol[i], a3);
                a4 = fmaf(lane_bcast(fv[rb + 4], i), wcol[i], a4);
                a5 = fmaf(lane_bcast(fv[rb + 5], i), wcol[i], a5);
                a6 = fmaf(lane_bcast(fv[rb + 6], i), wcol[i], a6);
                a7 = fmaf(lane_bcast(fv[rb + 7], i), wcol[i], a7);
            }
            float acc[8] = {a0, a1, a2, a3, a4, a5, a6, a7};
            #pragma unroll
            for (int j = 0; j < 8; ++j) {
                const int r   = w * 16 + rb + j;
                const int row = row0 + r;          // lane-invariant -> SALU
                const int b   = row / Ll;
                const int l   = row - b * Ll;
                const int d   = l / Pp;
                const int p   = l - d * Pp;
                float a = acc[j];
                a = fmaf((float)p, wcol[64], a);
                a = fmaf((float)d, wcol[65], a);
                sh[r * 65 + lane] = fmaxf(a, 0.f);
            }
        }
    }
    __syncthreads();

    // ---- phase 2a: enc dims 4w..4w+3 for all 64 rows; lane = row ----
    {
        float4 e4 = ((const float4*)b2)[w];
        const float4* w2v = (const float4*)w2;
        #pragma unroll 4
        for (int j = 0; j < 64; ++j) {
            const float hj = sh[lane * 65 + j];
            const float4 w4 = w2v[j * 4 + w];
            e4.x = fmaf(hj, w4.x, e4.x);
            e4.y = fmaf(hj, w4.y, e4.y);
            e4.z = fmaf(hj, w4.z, e4.z);
            e4.w = fmaf(hj, w4.w, e4.w);
        }
        se[lane * 17 + 4 * w + 0] = e4.x;
        se[lane * 17 + 4 * w + 1] = e4.y;
        se[lane * 17 + 4 * w + 2] = e4.z;
        se[lane * 17 + 4 * w + 3] = e4.w;
    }
    __syncthreads();

    // ---- phase 2b: lane = row; wave w -> qkv outputs 12w..12w+11 ----
    {
        float x[16];
        #pragma unroll
        for (int e = 0; e < 16; ++e) x[e] = se[lane * 17 + e];

        const int row = row0 + lane;
        const int b   = row / Ll;
        const int l   = row - b * Ll;

        float res[12];
        #pragma unroll
        for (int jj = 0; jj < 12; ++jj) {
            const int j = 12 * w + jj;
            const float4* wr = (const float4*)(w_qkv + j * 16);
            const float4 x0 = wr[0], x1 = wr[1], x2 = wr[2], x3 = wr[3];
            float a = b_qkv[j];
            a = fmaf(x[0],  x0.x, a); a = fmaf(x[1],  x0.y, a);
            a = fmaf(x[2],  x0.z, a); a = fmaf(x[3],  x0.w, a);
            a = fmaf(x[4],  x1.x, a); a = fmaf(x[5],  x1.y, a);
            a = fmaf(x[6],  x1.z, a); a = fmaf(x[7],  x1.w, a);
            a = fmaf(x[8],  x2.x, a); a = fmaf(x[9],  x2.y, a);
            a = fmaf(x[10], x2.z, a); a = fmaf(x[11], x2.w, a);
            a = fmaf(x[12], x3.x, a); a = fmaf(x[13], x3.y, a);
            a = fmaf(x[14], x3.z, a); a = fmaf(x[15], x3.w, a);
            res[jj] = a;
        }

        const float SC = 0.72134752044f;   // 0.5 * log2(e)
        #pragma unroll
        for (int m3 = 0; m3 < 3; ++m3) {
            const int m = 3 * w + m3;          // float4 group: tensor*4 + h
            const int tensor = m >> 2;
            const int h = m & 3;
            float4 vv = make_float4(res[4*m3+0], res[4*m3+1],
                                    res[4*m3+2], res[4*m3+3]);
            if (tensor == 0) { vv.x *= SC; vv.y *= SC; vv.z *= SC; vv.w *= SC; }
            float* basep = (tensor == 0) ? Q : (tensor == 1) ? K : V;
            *(float4*)(basep + (((size_t)(b * Hh + h)) * Ll + l) * HDim) = vv;
        }
    }
}

// ---------------------------------------------------------------------------
// Kernel B: attention + out-projection fused. Thread = (row, head):
// tid = 4r + c, block = (b, 64-row group), grid (128, 7). Each thread runs
// its head's 416-key softmax+PV loop (8-key register batches, blockIdx-
// uniform K/V addresses), then the row's 4 lanes exchange normalized head
// outputs via 4-lane __shfl and each lane computes 4 out-proj dims ->
// coalesced float4 store straight to d_out. Kills the ATT round-trip and
// the third kernel.
// ---------------------------------------------------------------------------
__global__ __launch_bounds__(256, 4) void attn_out_kernel(
    const float* __restrict__ Q, const float* __restrict__ K,
    const float* __restrict__ V, const float* __restrict__ w_out,
    const float* __restrict__ b_out, float* __restrict__ out)
{
    const int b   = blockIdx.x;           // 0..127
    const int g   = blockIdx.y;           // 0..6
    const int tid = threadIdx.x;
    const int r   = tid >> 2;             // row in group 0..63
    const int c   = tid & 3;              // head
    const int l   = g * 64 + r;
    if (l >= Ll) return;                  // g==6: waves 2,3 exit whole

    const int bh = b * Hh + c;
    const float4* __restrict__ Kb = (const float4*)K + (size_t)bh * Ll;
    const float4* __restrict__ Vb = (const float4*)V + (size_t)bh * Ll;
    const float4 q = ((const float4*)Q + (size_t)bh * Ll)[l];

    float s = 0.f;
    float4 o = make_float4(0.f, 0.f, 0.f, 0.f);

    for (int l0 = 0; l0 < Ll; l0 += 8) {   // 416 = 52*8
        float4 kk[8], vv[8];
        #pragma unroll
        for (int j = 0; j < 8; ++j) { kk[j] = Kb[l0 + j]; vv[j] = Vb[l0 + j]; }
        #pragma unroll
        for (int j = 0; j < 8; ++j) {
            float dot = q.x * kk[j].x;
            dot = fmaf(q.y, kk[j].y, dot);
            dot = fmaf(q.z, kk[j].z, dot);
            dot = fmaf(q.w, kk[j].w, dot);
            const float e = __builtin_amdgcn_exp2f(dot);
            s += e;
            o.x = fmaf(e, vv[j].x, o.x);
            o.y = fmaf(e, vv[j].y, o.y);
            o.z = fmaf(e, vv[j].z, o.z);
            o.w = fmaf(e, vv[j].w, o.w);
        }
    }

    // normalize this head's output
    const float inv = 1.0f / s;
    o.x *= inv; o.y *= inv; o.z *= inv; o.w *= inv;

    // gather the row's 16-dim attention output across the 4-lane group
    const int base = (tid & 63) & ~3;     // wave-relative lane of head 0
    const float4 x0 = make_float4(__shfl(o.x, base + 0), __shfl(o.y, base + 0),
                                  __shfl(o.z, base + 0), __shfl(o.w, base + 0));
    const float4 x1 = make_float4(__shfl(o.x, base + 1), __shfl(o.y, base + 1),
                                  __shfl(o.z, base + 1), __shfl(o.w, base + 1));
    const float4 x2 = make_float4(__shfl(o.x, base + 2), __shfl(o.y, base + 2),
                                  __shfl(o.z, base + 2), __shfl(o.w, base + 2));
    const float4 x3 = make_float4(__shfl(o.x, base + 3), __shfl(o.y, base + 3),
                                  __shfl(o.z, base + 3), __shfl(o.w, base + 3));

    // out dims 4c..4c+3: dot(x, w_out[od][:]), w_out rows contiguous, L1-hot
    const float4 bo = ((const float4*)b_out)[c];
    float4 res;
    {
        const float4* wr = (const float4*)(w_out + (4 * c + 0) * 16);
        const float4 wA = wr[0], wB = wr[1], wC = wr[2], wD = wr[3];
        float a = bo.x;
        a = fmaf(x0.x, wA.x, a); a = fmaf(x0.y, wA.y, a);
        a = fmaf(x0.z, wA.z, a); a = fmaf(x0.w, wA.w, a);
        a = fmaf(x1.x, wB.x, a); a = fmaf(x1.y, wB.y, a);
        a = fmaf(x1.z, wB.z, a); a = fmaf(x1.w, wB.w, a);
        a = fmaf(x2.x, wC.x, a); a = fmaf(x2.y, wC.y, a);
        a = fmaf(x2.z, wC.z, a); a = fmaf(x2.w, wC.w, a);
        a = fmaf(x3.x, wD.x, a); a = fmaf(x3.y, wD.y, a);
        a = fmaf(x3.z, wD.z, a); a = fmaf(x3.w, wD.w, a);
        res.x = a;
    }
    {
        const float4* wr = (const float4*)(w_out + (4 * c + 1) * 16);
        const float4 wA = wr[0], wB = wr[1], wC = wr[2], wD = wr[3];
        float a = bo.y;
        a = fmaf(x0.x, wA.x, a); a = fmaf(x0.y, wA.y, a);
        a = fmaf(x0.z, wA.z, a); a = fmaf(x0.w, wA.w, a);
        a = fmaf(x1.x, wB.x, a); a = fmaf(x1.y, wB.y, a);
        a = fmaf(x1.z, wB.z, a); a = fmaf(x1.w, wB.w, a);
        a = fmaf(x2.x, wC.x, a); a = fmaf(x2.y, wC.y, a);
        a = fmaf(x2.z, wC.z, a); a = fmaf(x2.w, wC.w, a);
        a = fmaf(x3.x, wD.x, a); a = fmaf(x3.y, wD.y, a);
        a = fmaf(x3.z, wD.z, a); a = fmaf(x3.w, wD.w, a);
        res.y = a;
    }
    {
        const float4* wr = (const float4*)(w_out + (4 * c + 2) * 16);
        const float4 wA = wr[0], wB = wr[1], wC = wr[2], wD = wr[3];
        float a = bo.z;
        a = fmaf(x0.x, wA.x, a); a = fmaf(x0.y, wA.y, a);
        a = fmaf(x0.z, wA.z, a); a = fmaf(x0.w, wA.w, a);
        a = fmaf(x1.x, wB.x, a); a = fmaf(x1.y, wB.y, a);
        a = fmaf(x1.z, wB.z, a); a = fmaf(x1.w, wB.w, a);
        a = fmaf(x2.x, wC.x, a); a = fmaf(x2.y, wC.y, a);
        a = fmaf(x2.z, wC.z, a); a = fmaf(x2.w, wC.w, a);
        a = fmaf(x3.x, wD.x, a); a = fmaf(x3.y, wD.y, a);
        a = fmaf(x3.z, wD.z, a); a = fmaf(x3.w, wD.w, a);
        res.z = a;
    }
    {
        const float4* wr = (const float4*)(w_out + (4 * c + 3) * 16);
        const float4 wA = wr[0], wB = wr[1], wC = wr[2], wD = wr[3];
        float a = bo.w;
        a = fmaf(x0.x, wA.x, a); a = fmaf(x0.y, wA.y, a);
        a = fmaf(x0.z, wA.z, a); a = fmaf(x0.w, wA.w, a);
        a = fmaf(x1.x, wB.x, a); a = fmaf(x1.y, wB.y, a);
        a = fmaf(x1.z, wB.z, a); a = fmaf(x1.w, wB.w, a);
        a = fmaf(x2.x, wC.x, a); a = fmaf(x2.y, wC.y, a);
        a = fmaf(x2.z, wC.z, a); a = fmaf(x2.w, wC.w, a);
        a = fmaf(x3.x, wD.x, a); a = fmaf(x3.y, wD.y, a);
        a = fmaf(x3.z, wD.z, a); a = fmaf(x3.w, wD.w, a);
        res.w = a;
    }

    // out[(b*Ll + l)*16 + 4c] -- consecutive float4 per tid: coalesced
    *(float4*)(out + ((size_t)(b * Ll + l)) * Ee + 4 * c) = res;
}

// ---------------------------------------------------------------------------
extern "C" void kernel_launch(void* const* d_in, const int* in_sizes, int n_in,
                              void* d_out, int out_size, void* d_ws, size_t ws_size,
                              hipStream_t stream) {
    const float* board = (const float*)d_in[0];
    const float* w1    = (const float*)d_in[1];
    const float* b1    = (const float*)d_in[2];
    const float* w2    = (const float*)d_in[3];
    const float* b2    = (const float*)d_in[4];
    const float* w_qkv = (const float*)d_in[5];
    const float* b_qkv = (const float*)d_in[6];
    const float* w_out = (const float*)d_in[7];
    const float* b_out = (const float*)d_in[8];
    float* out = (float*)d_out;

    float* ws  = (float*)d_ws;
    float* Q   = ws;                        // (B,H,L,HD)
    float* K   = ws + (size_t)Rr * Ee;
    float* V   = ws + (size_t)2 * Rr * Ee;

    hipLaunchKernelGGL(enc_qkv_kernel, dim3(Rr / 64), dim3(256), 0, stream,
                       board, w1, b1, w2, b2, w_qkv, b_qkv, Q, K, V);
    hipLaunchKernelGGL(attn_out_kernel, dim3(Bn, 7), dim3(256), 0, stream,
                       Q, K, V, w_out, b_out, out);
}

// Round 7
// 193.142 us; speedup vs baseline: 2.2000x; 2.2000x over previous
//
#include <hip/hip_runtime.h>

#define Bn 128
#define Dd 32
#define Pp 13
#define Ee 16
#define Hh 4
#define HDim 4
#define Ll 416           // Dd*Pp
#define Rr (Bn*Ll)       // 53248 rows

// ---------------------------------------------------------------------------
// Kernel A: fused encoder + QKV. 256 threads / 64 rows per block, 832 blocks.
//  stage: coop-load board tile -> LDS stride-65 (2-way bank = free).
//  phase1: lane = row. Each lane holds its row's 64 feats in VGPRs; wave w
//          computes hidden units w*16..w*16+15, 4 independent chains at a
//          time; ALL w1/b1 accesses are wave-uniform -> s_load + SGPR-operand
//          FMA (no readlane, no broadcast latency). h overwrites sf.
//  phase2a: lane=row; wave w computes enc dims 4w..4w+3 (se stride 17).
//  phase2b: lane=row; wave w computes qkv outputs 12w..12w+11; 3 coalesced
//          float4 stores. Q pre-scaled by 0.5*log2(e) for exp2 softmax.
// ---------------------------------------------------------------------------
__global__ __launch_bounds__(256, 4) void enc_qkv_kernel(
    const float* __restrict__ board, const float* __restrict__ w1,
    const float* __restrict__ b1, const float* __restrict__ w2,
    const float* __restrict__ b2, const float* __restrict__ w_qkv,
    const float* __restrict__ b_qkv,
    float* __restrict__ Q, float* __restrict__ K, float* __restrict__ V)
{
    __shared__ float sf[64 * 65];    // feats, then h (reused), stride 65
    __shared__ float se[64 * 17];    // enc, stride 17

    const int tid  = threadIdx.x;
    const int w    = tid >> 6;       // wave id 0..3
    const int lane = tid & 63;
    const int row0 = blockIdx.x * 64;

    // ---- stage: coalesced board tile -> LDS ----
    {
        const float4* bsrc = (const float4*)(board + (size_t)row0 * 64);
        #pragma unroll
        for (int k = 0; k < 4; ++k) {
            const int idx = tid + 256 * k;        // 0..1023
            const float4 v = bsrc[idx];
            float* dst = &sf[(idx >> 4) * 65 + 4 * (idx & 15)];
            dst[0] = v.x; dst[1] = v.y; dst[2] = v.z; dst[3] = v.w;
        }
    }
    __syncthreads();

    // per-lane row identity
    const int row = row0 + lane;
    const int bb  = row / Ll;
    const int ll  = row - bb * Ll;
    const int dd  = ll / Pp;
    const int pp  = ll - dd * Pp;
    const float fp = (float)pp, fd = (float)dd;

    // transpose feats into registers (2-way LDS reads = free)
    float f[64];
    #pragma unroll
    for (int i = 0; i < 64; ++i) f[i] = sf[lane * 65 + i];
    __syncthreads();   // sf free for h now

    // ---- phase 1: wave w -> hidden units w*16 .. w*16+15, 4 at a time ----
    #pragma unroll
    for (int q4 = 0; q4 < 4; ++q4) {
        const int u0 = w * 16 + q4 * 4;
        float a0 = b1[u0 + 0], a1 = b1[u0 + 1];
        float a2 = b1[u0 + 2], a3 = b1[u0 + 3];
        #pragma unroll
        for (int i = 0; i < 64; ++i) {
            const float4 wv = *(const float4*)(w1 + i * 64 + u0); // uniform -> s_load
            a0 = fmaf(f[i], wv.x, a0);
            a1 = fmaf(f[i], wv.y, a1);
            a2 = fmaf(f[i], wv.z, a2);
            a3 = fmaf(f[i], wv.w, a3);
        }
        {
            const float4 wv = *(const float4*)(w1 + 64 * 64 + u0);
            a0 = fmaf(fp, wv.x, a0); a1 = fmaf(fp, wv.y, a1);
            a2 = fmaf(fp, wv.z, a2); a3 = fmaf(fp, wv.w, a3);
        }
        {
            const float4 wv = *(const float4*)(w1 + 65 * 64 + u0);
            a0 = fmaf(fd, wv.x, a0); a1 = fmaf(fd, wv.y, a1);
            a2 = fmaf(fd, wv.z, a2); a3 = fmaf(fd, wv.w, a3);
        }
        sf[lane * 65 + u0 + 0] = fmaxf(a0, 0.f);
        sf[lane * 65 + u0 + 1] = fmaxf(a1, 0.f);
        sf[lane * 65 + u0 + 2] = fmaxf(a2, 0.f);
        sf[lane * 65 + u0 + 3] = fmaxf(a3, 0.f);
    }
    __syncthreads();

    // ---- phase 2a: enc dims 4w..4w+3 for all 64 rows; lane = row ----
    {
        float4 e4 = ((const float4*)b2)[w];
        const float4* w2v = (const float4*)w2;
        #pragma unroll 4
        for (int j = 0; j < 64; ++j) {
            const float hj = sf[lane * 65 + j];   // 2-way = free
            const float4 w4 = w2v[j * 4 + w];     // uniform -> s_load
            e4.x = fmaf(hj, w4.x, e4.x);
            e4.y = fmaf(hj, w4.y, e4.y);
            e4.z = fmaf(hj, w4.z, e4.z);
            e4.w = fmaf(hj, w4.w, e4.w);
        }
        se[lane * 17 + 4 * w + 0] = e4.x;
        se[lane * 17 + 4 * w + 1] = e4.y;
        se[lane * 17 + 4 * w + 2] = e4.z;
        se[lane * 17 + 4 * w + 3] = e4.w;
    }
    __syncthreads();

    // ---- phase 2b: lane = row; wave w -> qkv outputs 12w..12w+11 ----
    {
        float x[16];
        #pragma unroll
        for (int e = 0; e < 16; ++e) x[e] = se[lane * 17 + e];

        float res[12];
        #pragma unroll
        for (int jj = 0; jj < 12; ++jj) {
            const int j = 12 * w + jj;
            const float4* wr = (const float4*)(w_qkv + j * 16);  // uniform
            const float4 x0 = wr[0], x1 = wr[1], x2 = wr[2], x3 = wr[3];
            float a = b_qkv[j];
            a = fmaf(x[0],  x0.x, a); a = fmaf(x[1],  x0.y, a);
            a = fmaf(x[2],  x0.z, a); a = fmaf(x[3],  x0.w, a);
            a = fmaf(x[4],  x1.x, a); a = fmaf(x[5],  x1.y, a);
            a = fmaf(x[6],  x1.z, a); a = fmaf(x[7],  x1.w, a);
            a = fmaf(x[8],  x2.x, a); a = fmaf(x[9],  x2.y, a);
            a = fmaf(x[10], x2.z, a); a = fmaf(x[11], x2.w, a);
            a = fmaf(x[12], x3.x, a); a = fmaf(x[13], x3.y, a);
            a = fmaf(x[14], x3.z, a); a = fmaf(x[15], x3.w, a);
            res[jj] = a;
        }

        const float SC = 0.72134752044f;   // 0.5 * log2(e)
        #pragma unroll
        for (int m3 = 0; m3 < 3; ++m3) {
            const int m = 3 * w + m3;          // float4 group: tensor*4 + h
            const int tensor = m >> 2;
            const int h = m & 3;
            float4 vv = make_float4(res[4*m3+0], res[4*m3+1],
                                    res[4*m3+2], res[4*m3+3]);
            if (tensor == 0) { vv.x *= SC; vv.y *= SC; vv.z *= SC; vv.w *= SC; }
            float* basep = (tensor == 0) ? Q : (tensor == 1) ? K : V;
            *(float4*)(basep + (((size_t)(bb * Hh + h)) * Ll + ll) * HDim) = vv;
        }
    }
}

// ---------------------------------------------------------------------------
// Kernel B: attention (r5 structure: blockIdx-uniform K/V addresses ->
// scalarized s_load batches) + explicit ping-pong double buffer of 4-key
// chunks so next-chunk loads issue before current-chunk FMAs.
// Max-free single-pass softmax (scores tiny; softmax shift-invariant).
// ---------------------------------------------------------------------------
#define LOADCH(kd0,kd1,kd2,kd3,vd0,vd1,vd2,vd3,c)                 \
    { const int _l0 = (c) * 4;                                    \
      kd0 = Kb[_l0 + 0]; kd1 = Kb[_l0 + 1];                       \
      kd2 = Kb[_l0 + 2]; kd3 = Kb[_l0 + 3];                       \
      vd0 = Vb[_l0 + 0]; vd1 = Vb[_l0 + 1];                       \
      vd2 = Vb[_l0 + 2]; vd3 = Vb[_l0 + 3]; }

#define COMPCH(kd0,kd1,kd2,kd3,vd0,vd1,vd2,vd3)                   \
    { const float4 _kk[4] = {kd0, kd1, kd2, kd3};                 \
      const float4 _vv[4] = {vd0, vd1, vd2, vd3};                 \
      _Pragma("unroll")                                           \
      for (int _j = 0; _j < 4; ++_j) {                            \
          float dot = q.x * _kk[_j].x;                            \
          dot = fmaf(q.y, _kk[_j].y, dot);                        \
          dot = fmaf(q.z, _kk[_j].z, dot);                        \
          dot = fmaf(q.w, _kk[_j].w, dot);                        \
          const float e = __builtin_amdgcn_exp2f(dot);            \
          s += e;                                                 \
          o.x = fmaf(e, _vv[_j].x, o.x);                          \
          o.y = fmaf(e, _vv[_j].y, o.y);                          \
          o.z = fmaf(e, _vv[_j].z, o.z);                          \
          o.w = fmaf(e, _vv[_j].w, o.w);                          \
      } }

__global__ __launch_bounds__(256, 4) void attn_kernel(
    const float* __restrict__ Q, const float* __restrict__ K,
    const float* __restrict__ V, float* __restrict__ ATT)
{
    const int bh   = blockIdx.x;          // b*Hh + h (wave-uniform)
    const int half = blockIdx.y;          // 0/1
    const int tid  = threadIdx.x;
    if (tid >= 208) return;
    const int qi = half * 208 + tid;      // 0..415 across the two halves

    const float4* __restrict__ Kb = (const float4*)K + (size_t)bh * Ll;
    const float4* __restrict__ Vb = (const float4*)V + (size_t)bh * Ll;
    const float4 q = ((const float4*)Q + (size_t)bh * Ll)[qi];

    float s = 0.f;
    float4 o = make_float4(0.f, 0.f, 0.f, 0.f);

    float4 kA0,kA1,kA2,kA3, vA0,vA1,vA2,vA3;
    float4 kB0,kB1,kB2,kB3, vB0,vB1,vB2,vB3;

    LOADCH(kA0,kA1,kA2,kA3,vA0,vA1,vA2,vA3, 0);
    for (int c = 0; c < 104; c += 2) {        // 104 chunks of 4 keys = 416
        LOADCH(kB0,kB1,kB2,kB3,vB0,vB1,vB2,vB3, c + 1);
        COMPCH(kA0,kA1,kA2,kA3,vA0,vA1,vA2,vA3);
        if (c + 2 < 104)
            LOADCH(kA0,kA1,kA2,kA3,vA0,vA1,vA2,vA3, c + 2);
        COMPCH(kB0,kB1,kB2,kB3,vB0,vB1,vB2,vB3);
    }

    const int b = bh >> 2;
    const int h = bh & 3;
    const float inv = 1.0f / s;
    *(float4*)(ATT + ((size_t)(b * Ll + qi)) * Ee + h * HDim) =
        make_float4(o.x * inv, o.y * inv, o.z * inv, o.w * inv);
}

// ---------------------------------------------------------------------------
// Kernel C: out projection (16x16 GEMV per row; LDS-transposed w_out).
// ---------------------------------------------------------------------------
__global__ __launch_bounds__(256, 8) void outproj_kernel(
    const float* __restrict__ ATT, const float* __restrict__ w_out,
    const float* __restrict__ b_out, float* __restrict__ out)
{
    __shared__ float sx[256];
    __shared__ float sw[256];   // sw[e*16+o] = w_out[o*16+e]

    const int tid = threadIdx.x;
    const size_t gbase = (size_t)blockIdx.x * 256;
    sx[tid] = ATT[gbase + tid];
    sw[tid] = w_out[(tid & 15) * 16 + (tid >> 4)];
    __syncthreads();

    const int rloc = tid >> 4;
    const int o = tid & 15;
    float acc = b_out[o];
    #pragma unroll
    for (int e = 0; e < 16; ++e)
        acc = fmaf(sx[rloc * 16 + e], sw[e * 16 + o], acc);
    out[gbase + tid] = acc;
}

// ---------------------------------------------------------------------------
extern "C" void kernel_launch(void* const* d_in, const int* in_sizes, int n_in,
                              void* d_out, int out_size, void* d_ws, size_t ws_size,
                              hipStream_t stream) {
    const float* board = (const float*)d_in[0];
    const float* w1    = (const float*)d_in[1];
    const float* b1    = (const float*)d_in[2];
    const float* w2    = (const float*)d_in[3];
    const float* b2    = (const float*)d_in[4];
    const float* w_qkv = (const float*)d_in[5];
    const float* b_qkv = (const float*)d_in[6];
    const float* w_out = (const float*)d_in[7];
    const float* b_out = (const float*)d_in[8];
    float* out = (float*)d_out;

    float* ws  = (float*)d_ws;
    float* Q   = ws;                        // (B,H,L,HD)
    float* K   = ws + (size_t)Rr * Ee;
    float* V   = ws + (size_t)2 * Rr * Ee;
    float* ATT = ws + (size_t)3 * Rr * Ee;  // (B,L,E)

    hipLaunchKernelGGL(enc_qkv_kernel, dim3(Rr / 64), dim3(256), 0, stream,
                       board, w1, b1, w2, b2, w_qkv, b_qkv, Q, K, V);
    hipLaunchKernelGGL(attn_kernel, dim3(Bn * Hh, 2), dim3(256), 0, stream,
                       Q, K, V, ATT);
    hipLaunchKernelGGL(outproj_kernel, dim3((Rr * Ee) / 256), dim3(256), 0, stream,
                       ATT, w_out, b_out, out);
}

// Round 9
// 169.527 us; speedup vs baseline: 2.5065x; 1.1393x over previous
//
#include <hip/hip_runtime.h>

#define Bn 128
#define Dd 32
#define Pp 13
#define Ee 16
#define Hh 4
#define HDim 4
#define Ll 416           // Dd*Pp
#define Rr (Bn*Ll)       // 53248 rows

// ---------------------------------------------------------------------------
// Kernel A: fused encoder + QKV. 256 threads / 64 rows per block, 832 blocks.
// All weight addresses are routed through readfirstlane(w) so the compiler
// can PROVE wave-uniformity -> s_load (scalar) weight streams, exactly like
// attn's blockIdx-uniform K/V loads (which scalarized to VGPR=12).
// ---------------------------------------------------------------------------
__global__ __launch_bounds__(256, 4) void enc_qkv_kernel(
    const float* __restrict__ board, const float* __restrict__ w1,
    const float* __restrict__ b1, const float* __restrict__ w2,
    const float* __restrict__ b2, const float* __restrict__ w_qkv,
    const float* __restrict__ b_qkv,
    float* __restrict__ Q, float* __restrict__ K, float* __restrict__ V)
{
    __shared__ float sf[64 * 65];    // feats, then h (reused), stride 65
    __shared__ float se[64 * 17];    // enc, stride 17

    const int tid  = threadIdx.x;
    const int wu   = __builtin_amdgcn_readfirstlane(tid >> 6);  // uniform wave id
    const int lane = tid & 63;
    const int row0 = blockIdx.x * 64;

    // ---- stage: coalesced board tile -> LDS ----
    {
        const float4* bsrc = (const float4*)(board + (size_t)row0 * 64);
        #pragma unroll
        for (int k = 0; k < 4; ++k) {
            const int idx = tid + 256 * k;        // 0..1023
            const float4 v = bsrc[idx];
            float* dst = &sf[(idx >> 4) * 65 + 4 * (idx & 15)];
            dst[0] = v.x; dst[1] = v.y; dst[2] = v.z; dst[3] = v.w;
        }
    }
    __syncthreads();

    // per-lane row identity
    const int row = row0 + lane;
    const int bb  = row / Ll;
    const int ll  = row - bb * Ll;
    const int dd  = ll / Pp;
    const int pp  = ll - dd * Pp;
    const float fp = (float)pp, fd = (float)dd;

    // transpose feats into registers (2-way LDS reads = free)
    float f[64];
    #pragma unroll
    for (int i = 0; i < 64; ++i) f[i] = sf[lane * 65 + i];
    __syncthreads();   // sf free for h now

    // ---- phase 1: wave wu -> hidden units wu*16 .. wu*16+15, 4 at a time ----
    #pragma unroll
    for (int q4 = 0; q4 < 4; ++q4) {
        const int u0 = wu * 16 + q4 * 4;          // uniform
        float a0 = b1[u0 + 0], a1 = b1[u0 + 1];
        float a2 = b1[u0 + 2], a3 = b1[u0 + 3];
        #pragma unroll
        for (int i = 0; i < 64; ++i) {
            const float4 wv = *(const float4*)(w1 + i * 64 + u0); // s_load
            a0 = fmaf(f[i], wv.x, a0);
            a1 = fmaf(f[i], wv.y, a1);
            a2 = fmaf(f[i], wv.z, a2);
            a3 = fmaf(f[i], wv.w, a3);
        }
        {
            const float4 wv = *(const float4*)(w1 + 64 * 64 + u0);
            a0 = fmaf(fp, wv.x, a0); a1 = fmaf(fp, wv.y, a1);
            a2 = fmaf(fp, wv.z, a2); a3 = fmaf(fp, wv.w, a3);
        }
        {
            const float4 wv = *(const float4*)(w1 + 65 * 64 + u0);
            a0 = fmaf(fd, wv.x, a0); a1 = fmaf(fd, wv.y, a1);
            a2 = fmaf(fd, wv.z, a2); a3 = fmaf(fd, wv.w, a3);
        }
        sf[lane * 65 + u0 + 0] = fmaxf(a0, 0.f);
        sf[lane * 65 + u0 + 1] = fmaxf(a1, 0.f);
        sf[lane * 65 + u0 + 2] = fmaxf(a2, 0.f);
        sf[lane * 65 + u0 + 3] = fmaxf(a3, 0.f);
    }
    __syncthreads();

    // ---- phase 2a: enc dims 4wu..4wu+3 for all 64 rows; lane = row ----
    {
        float4 e4 = *(const float4*)(b2 + 4 * wu);
        #pragma unroll 4
        for (int j = 0; j < 64; ++j) {
            const float hj = sf[lane * 65 + j];   // 2-way = free
            const float4 w4 = *(const float4*)(w2 + j * 16 + 4 * wu); // s_load
            e4.x = fmaf(hj, w4.x, e4.x);
            e4.y = fmaf(hj, w4.y, e4.y);
            e4.z = fmaf(hj, w4.z, e4.z);
            e4.w = fmaf(hj, w4.w, e4.w);
        }
        se[lane * 17 + 4 * wu + 0] = e4.x;
        se[lane * 17 + 4 * wu + 1] = e4.y;
        se[lane * 17 + 4 * wu + 2] = e4.z;
        se[lane * 17 + 4 * wu + 3] = e4.w;
    }
    __syncthreads();

    // ---- phase 2b: lane = row; wave wu -> qkv outputs 12wu..12wu+11 ----
    {
        float x[16];
        #pragma unroll
        for (int e = 0; e < 16; ++e) x[e] = se[lane * 17 + e];

        float res[12];
        #pragma unroll
        for (int jj = 0; jj < 12; ++jj) {
            const int j = 12 * wu + jj;                          // uniform
            const float4* wr = (const float4*)(w_qkv + j * 16);  // s_load
            const float4 x0 = wr[0], x1 = wr[1], x2 = wr[2], x3 = wr[3];
            float a = b_qkv[j];
            a = fmaf(x[0],  x0.x, a); a = fmaf(x[1],  x0.y, a);
            a = fmaf(x[2],  x0.z, a); a = fmaf(x[3],  x0.w, a);
            a = fmaf(x[4],  x1.x, a); a = fmaf(x[5],  x1.y, a);
            a = fmaf(x[6],  x1.z, a); a = fmaf(x[7],  x1.w, a);
            a = fmaf(x[8],  x2.x, a); a = fmaf(x[9],  x2.y, a);
            a = fmaf(x[10], x2.z, a); a = fmaf(x[11], x2.w, a);
            a = fmaf(x[12], x3.x, a); a = fmaf(x[13], x3.y, a);
            a = fmaf(x[14], x3.z, a); a = fmaf(x[15], x3.w, a);
            res[jj] = a;
        }

        const float SC = 0.72134752044f;   // 0.5 * log2(e)
        #pragma unroll
        for (int m3 = 0; m3 < 3; ++m3) {
            const int m = 3 * wu + m3;         // float4 group: tensor*4 + h
            const int tensor = m >> 2;
            const int h = m & 3;
            float4 vv = make_float4(res[4*m3+0], res[4*m3+1],
                                    res[4*m3+2], res[4*m3+3]);
            if (tensor == 0) { vv.x *= SC; vv.y *= SC; vv.z *= SC; vv.w *= SC; }
            float* basep = (tensor == 0) ? Q : (tensor == 1) ? K : V;
            *(float4*)(basep + (((size_t)(bb * Hh + h)) * Ll + ll) * HDim) = vv;
        }
    }
}

// ---------------------------------------------------------------------------
// Kernel B: attention. 64-thread blocks (full-wave lanes), grid (512 bh, 7
// row-groups). K/V addresses are blockIdx-uniform -> s_load scalar batches.
// Explicit 3-buffer rotation, loads issued 2 chunks (>=208 cyc) ahead of use.
// Max-free single-pass softmax (scores tiny; softmax shift-invariant).
// ---------------------------------------------------------------------------
#define LOADC(K0,K1,K2,K3,V0,V1,V2,V3,c)                          \
    { const int _l0 = (c) * 4;                                    \
      K0 = Kb[_l0 + 0]; K1 = Kb[_l0 + 1];                         \
      K2 = Kb[_l0 + 2]; K3 = Kb[_l0 + 3];                         \
      V0 = Vb[_l0 + 0]; V1 = Vb[_l0 + 1];                         \
      V2 = Vb[_l0 + 2]; V3 = Vb[_l0 + 3]; }

#define COMPC(K0,K1,K2,K3,V0,V1,V2,V3)                            \
    { const float4 _kk[4] = {K0, K1, K2, K3};                     \
      const float4 _vv[4] = {V0, V1, V2, V3};                     \
      _Pragma("unroll")                                           \
      for (int _j = 0; _j < 4; ++_j) {                            \
          float dot = q.x * _kk[_j].x;                            \
          dot = fmaf(q.y, _kk[_j].y, dot);                        \
          dot = fmaf(q.z, _kk[_j].z, dot);                        \
          dot = fmaf(q.w, _kk[_j].w, dot);                        \
          const float e = __builtin_amdgcn_exp2f(dot);            \
          s += e;                                                 \
          o.x = fmaf(e, _vv[_j].x, o.x);                          \
          o.y = fmaf(e, _vv[_j].y, o.y);                          \
          o.z = fmaf(e, _vv[_j].z, o.z);                          \
          o.w = fmaf(e, _vv[_j].w, o.w);                          \
      } }

__global__ __launch_bounds__(64, 8) void attn_kernel(
    const float* __restrict__ Q, const float* __restrict__ K,
    const float* __restrict__ V, float* __restrict__ ATT)
{
    const int bh   = blockIdx.x;          // b*Hh + h (block-uniform)
    const int g    = blockIdx.y;          // 0..6
    const int lane = threadIdx.x;         // 0..63
    const int qi   = g * 64 + lane;
    if (qi >= Ll) return;                 // only group 6 is partial

    const float4* __restrict__ Kb = (const float4*)K + (size_t)bh * Ll;
    const float4* __restrict__ Vb = (const float4*)V + (size_t)bh * Ll;
    const float4 q = ((const float4*)Q + (size_t)bh * Ll)[qi];

    float s = 0.f;
    float4 o = make_float4(0.f, 0.f, 0.f, 0.f);

    float4 kA0,kA1,kA2,kA3, vA0,vA1,vA2,vA3;
    float4 kB0,kB1,kB2,kB3, vB0,vB1,vB2,vB3;
    float4 kC0,kC1,kC2,kC3, vC0,vC1,vC2,vC3;

    LOADC(kA0,kA1,kA2,kA3,vA0,vA1,vA2,vA3, 0);
    LOADC(kB0,kB1,kB2,kB3,vB0,vB1,vB2,vB3, 1);
    // 104 chunks of 4 keys; 34 iterations x 3 chunks = 102, epilogue 2.
    #pragma unroll 1
    for (int c = 0; c < 102; c += 3) {
        LOADC(kC0,kC1,kC2,kC3,vC0,vC1,vC2,vC3, c + 2);
        COMPC(kA0,kA1,kA2,kA3,vA0,vA1,vA2,vA3);
        LOADC(kA0,kA1,kA2,kA3,vA0,vA1,vA2,vA3, c + 3);
        COMPC(kB0,kB1,kB2,kB3,vB0,vB1,vB2,vB3);
        LOADC(kB0,kB1,kB2,kB3,vB0,vB1,vB2,vB3, c + 4);
        COMPC(kC0,kC1,kC2,kC3,vC0,vC1,vC2,vC3);
    }
    COMPC(kA0,kA1,kA2,kA3,vA0,vA1,vA2,vA3);   // chunk 102
    COMPC(kB0,kB1,kB2,kB3,vB0,vB1,vB2,vB3);   // chunk 103

    const int b = bh >> 2;
    const int h = bh & 3;
    const float inv = 1.0f / s;
    *(float4*)(ATT + ((size_t)(b * Ll + qi)) * Ee + h * HDim) =
        make_float4(o.x * inv, o.y * inv, o.z * inv, o.w * inv);
}

// ---------------------------------------------------------------------------
// Kernel C: out projection (16x16 GEMV per row; LDS-transposed w_out).
// ---------------------------------------------------------------------------
__global__ __launch_bounds__(256, 8) void outproj_kernel(
    const float* __restrict__ ATT, const float* __restrict__ w_out,
    const float* __restrict__ b_out, float* __restrict__ out)
{
    __shared__ float sx[256];
    __shared__ float sw[256];   // sw[e*16+o] = w_out[o*16+e]

    const int tid = threadIdx.x;
    const size_t gbase = (size_t)blockIdx.x * 256;
    sx[tid] = ATT[gbase + tid];
    sw[tid] = w_out[(tid & 15) * 16 + (tid >> 4)];
    __syncthreads();

    const int rloc = tid >> 4;
    const int o = tid & 15;
    float acc = b_out[o];
    #pragma unroll
    for (int e = 0; e < 16; ++e)
        acc = fmaf(sx[rloc * 16 + e], sw[e * 16 + o], acc);
    out[gbase + tid] = acc;
}

// ---------------------------------------------------------------------------
extern "C" void kernel_launch(void* const* d_in, const int* in_sizes, int n_in,
                              void* d_out, int out_size, void* d_ws, size_t ws_size,
                              hipStream_t stream) {
    const float* board = (const float*)d_in[0];
    const float* w1    = (const float*)d_in[1];
    const float* b1    = (const float*)d_in[2];
    const float* w2    = (const float*)d_in[3];
    const float* b2    = (const float*)d_in[4];
    const float* w_qkv = (const float*)d_in[5];
    const float* b_qkv = (const float*)d_in[6];
    const float* w_out = (const float*)d_in[7];
    const float* b_out = (const float*)d_in[8];
    float* out = (float*)d_out;

    float* ws  = (float*)d_ws;
    float* Q   = ws;                        // (B,H,L,HD)
    float* K   = ws + (size_t)Rr * Ee;
    float* V   = ws + (size_t)2 * Rr * Ee;
    float* ATT = ws + (size_t)3 * Rr * Ee;  // (B,L,E)

    hipLaunchKernelGGL(enc_qkv_kernel, dim3(Rr / 64), dim3(256), 0, stream,
                       board, w1, b1, w2, b2, w_qkv, b_qkv, Q, K, V);
    hipLaunchKernelGGL(attn_kernel, dim3(Bn * Hh, 7), dim3(64), 0, stream,
                       Q, K, V, ATT);
    hipLaunchKernelGGL(outproj_kernel, dim3((Rr * Ee) / 256), dim3(256), 0, stream,
                       ATT, w_out, b_out, out);
}

// Round 10
// 136.273 us; speedup vs baseline: 3.1181x; 1.2440x over previous
//
#include <hip/hip_runtime.h>

#define Bn 128
#define Dd 32
#define Pp 13
#define Ee 16
#define Hh 4
#define HDim 4
#define Ll 416           // Dd*Pp
#define Rr (Bn*Ll)       // 53248 rows

// ---------------------------------------------------------------------------
// Kernel A: fused encoder + QKV (r9 version — readfirstlane-uniform weights).
// ---------------------------------------------------------------------------
__global__ __launch_bounds__(256, 4) void enc_qkv_kernel(
    const float* __restrict__ board, const float* __restrict__ w1,
    const float* __restrict__ b1, const float* __restrict__ w2,
    const float* __restrict__ b2, const float* __restrict__ w_qkv,
    const float* __restrict__ b_qkv,
    float* __restrict__ Q, float* __restrict__ K, float* __restrict__ V)
{
    __shared__ float sf[64 * 65];    // feats, then h (reused), stride 65
    __shared__ float se[64 * 17];    // enc, stride 17

    const int tid  = threadIdx.x;
    const int wu   = __builtin_amdgcn_readfirstlane(tid >> 6);  // uniform wave id
    const int lane = tid & 63;
    const int row0 = blockIdx.x * 64;

    // ---- stage: coalesced board tile -> LDS ----
    {
        const float4* bsrc = (const float4*)(board + (size_t)row0 * 64);
        #pragma unroll
        for (int k = 0; k < 4; ++k) {
            const int idx = tid + 256 * k;        // 0..1023
            const float4 v = bsrc[idx];
            float* dst = &sf[(idx >> 4) * 65 + 4 * (idx & 15)];
            dst[0] = v.x; dst[1] = v.y; dst[2] = v.z; dst[3] = v.w;
        }
    }
    __syncthreads();

    // per-lane row identity
    const int row = row0 + lane;
    const int bb  = row / Ll;
    const int ll  = row - bb * Ll;
    const int dd  = ll / Pp;
    const int pp  = ll - dd * Pp;
    const float fp = (float)pp, fd = (float)dd;

    // transpose feats into registers (2-way LDS reads = free)
    float f[64];
    #pragma unroll
    for (int i = 0; i < 64; ++i) f[i] = sf[lane * 65 + i];
    __syncthreads();   // sf free for h now

    // ---- phase 1: wave wu -> hidden units wu*16 .. wu*16+15, 4 at a time ----
    #pragma unroll
    for (int q4 = 0; q4 < 4; ++q4) {
        const int u0 = wu * 16 + q4 * 4;          // uniform
        float a0 = b1[u0 + 0], a1 = b1[u0 + 1];
        float a2 = b1[u0 + 2], a3 = b1[u0 + 3];
        #pragma unroll
        for (int i = 0; i < 64; ++i) {
            const float4 wv = *(const float4*)(w1 + i * 64 + u0); // s_load
            a0 = fmaf(f[i], wv.x, a0);
            a1 = fmaf(f[i], wv.y, a1);
            a2 = fmaf(f[i], wv.z, a2);
            a3 = fmaf(f[i], wv.w, a3);
        }
        {
            const float4 wv = *(const float4*)(w1 + 64 * 64 + u0);
            a0 = fmaf(fp, wv.x, a0); a1 = fmaf(fp, wv.y, a1);
            a2 = fmaf(fp, wv.z, a2); a3 = fmaf(fp, wv.w, a3);
        }
        {
            const float4 wv = *(const float4*)(w1 + 65 * 64 + u0);
            a0 = fmaf(fd, wv.x, a0); a1 = fmaf(fd, wv.y, a1);
            a2 = fmaf(fd, wv.z, a2); a3 = fmaf(fd, wv.w, a3);
        }
        sf[lane * 65 + u0 + 0] = fmaxf(a0, 0.f);
        sf[lane * 65 + u0 + 1] = fmaxf(a1, 0.f);
        sf[lane * 65 + u0 + 2] = fmaxf(a2, 0.f);
        sf[lane * 65 + u0 + 3] = fmaxf(a3, 0.f);
    }
    __syncthreads();

    // ---- phase 2a: enc dims 4wu..4wu+3 for all 64 rows; lane = row ----
    {
        float4 e4 = *(const float4*)(b2 + 4 * wu);
        #pragma unroll 4
        for (int j = 0; j < 64; ++j) {
            const float hj = sf[lane * 65 + j];   // 2-way = free
            const float4 w4 = *(const float4*)(w2 + j * 16 + 4 * wu); // s_load
            e4.x = fmaf(hj, w4.x, e4.x);
            e4.y = fmaf(hj, w4.y, e4.y);
            e4.z = fmaf(hj, w4.z, e4.z);
            e4.w = fmaf(hj, w4.w, e4.w);
        }
        se[lane * 17 + 4 * wu + 0] = e4.x;
        se[lane * 17 + 4 * wu + 1] = e4.y;
        se[lane * 17 + 4 * wu + 2] = e4.z;
        se[lane * 17 + 4 * wu + 3] = e4.w;
    }
    __syncthreads();

    // ---- phase 2b: lane = row; wave wu -> qkv outputs 12wu..12wu+11 ----
    {
        float x[16];
        #pragma unroll
        for (int e = 0; e < 16; ++e) x[e] = se[lane * 17 + e];

        float res[12];
        #pragma unroll
        for (int jj = 0; jj < 12; ++jj) {
            const int j = 12 * wu + jj;                          // uniform
            const float4* wr = (const float4*)(w_qkv + j * 16);  // s_load
            const float4 x0 = wr[0], x1 = wr[1], x2 = wr[2], x3 = wr[3];
            float a = b_qkv[j];
            a = fmaf(x[0],  x0.x, a); a = fmaf(x[1],  x0.y, a);
            a = fmaf(x[2],  x0.z, a); a = fmaf(x[3],  x0.w, a);
            a = fmaf(x[4],  x1.x, a); a = fmaf(x[5],  x1.y, a);
            a = fmaf(x[6],  x1.z, a); a = fmaf(x[7],  x1.w, a);
            a = fmaf(x[8],  x2.x, a); a = fmaf(x[9],  x2.y, a);
            a = fmaf(x[10], x2.z, a); a = fmaf(x[11], x2.w, a);
            a = fmaf(x[12], x3.x, a); a = fmaf(x[13], x3.y, a);
            a = fmaf(x[14], x3.z, a); a = fmaf(x[15], x3.w, a);
            res[jj] = a;
        }

        const float SC = 0.72134752044f;   // 0.5 * log2(e)
        #pragma unroll
        for (int m3 = 0; m3 < 3; ++m3) {
            const int m = 3 * wu + m3;         // float4 group: tensor*4 + h
            const int tensor = m >> 2;
            const int h = m & 3;
            float4 vv = make_float4(res[4*m3+0], res[4*m3+1],
                                    res[4*m3+2], res[4*m3+3]);
            if (tensor == 0) { vv.x *= SC; vv.y *= SC; vv.z *= SC; vv.w *= SC; }
            float* basep = (tensor == 0) ? Q : (tensor == 1) ? K : V;
            *(float4*)(basep + (((size_t)(bb * Hh + h)) * Ll + ll) * HDim) = vv;
        }
    }
}

// ---------------------------------------------------------------------------
// Kernel B: attention — EXACT r5 structure (best measured: ~44 us).
// blockIdx-uniform K/V addresses -> compiler scalarizes to s_load batches;
// plain sequential 8-key batches, compiler-scheduled (hand-pipelining the
// rotation in r7/r9 inflated the VALU stream 2.3x — do not reintroduce).
// Max-free single-pass softmax (scores tiny; softmax shift-invariant).
// ---------------------------------------------------------------------------
__global__ __launch_bounds__(256, 8) void attn_kernel(
    const float* __restrict__ Q, const float* __restrict__ K,
    const float* __restrict__ V, float* __restrict__ ATT)
{
    const int bh   = blockIdx.x;          // b*Hh + h
    const int half = blockIdx.y;          // 0/1
    const int tid  = threadIdx.x;
    if (tid >= 208) return;
    const int qi = half * 208 + tid;      // 0..415 across the two halves

    const float4* __restrict__ Kb = (const float4*)K + (size_t)bh * Ll;
    const float4* __restrict__ Vb = (const float4*)V + (size_t)bh * Ll;
    const float4 q = ((const float4*)Q + (size_t)bh * Ll)[qi];

    float s = 0.f;
    float4 o = make_float4(0.f, 0.f, 0.f, 0.f);

    for (int l0 = 0; l0 < Ll; l0 += 8) {   // 416 = 52*8
        float4 kk[8], vv[8];
        #pragma unroll
        for (int j = 0; j < 8; ++j) { kk[j] = Kb[l0 + j]; vv[j] = Vb[l0 + j]; }
        #pragma unroll
        for (int j = 0; j < 8; ++j) {
            float dot = q.x * kk[j].x;
            dot = fmaf(q.y, kk[j].y, dot);
            dot = fmaf(q.z, kk[j].z, dot);
            dot = fmaf(q.w, kk[j].w, dot);
            const float e = __builtin_amdgcn_exp2f(dot);
            s += e;
            o.x = fmaf(e, vv[j].x, o.x);
            o.y = fmaf(e, vv[j].y, o.y);
            o.z = fmaf(e, vv[j].z, o.z);
            o.w = fmaf(e, vv[j].w, o.w);
        }
    }

    const int b = bh >> 2;
    const int h = bh & 3;
    const float inv = 1.0f / s;
    *(float4*)(ATT + ((size_t)(b * Ll + qi)) * Ee + h * HDim) =
        make_float4(o.x * inv, o.y * inv, o.z * inv, o.w * inv);
}

// ---------------------------------------------------------------------------
// Kernel C: out projection (16x16 GEMV per row; LDS-transposed w_out).
// ---------------------------------------------------------------------------
__global__ __launch_bounds__(256, 8) void outproj_kernel(
    const float* __restrict__ ATT, const float* __restrict__ w_out,
    const float* __restrict__ b_out, float* __restrict__ out)
{
    __shared__ float sx[256];
    __shared__ float sw[256];   // sw[e*16+o] = w_out[o*16+e]

    const int tid = threadIdx.x;
    const size_t gbase = (size_t)blockIdx.x * 256;
    sx[tid] = ATT[gbase + tid];
    sw[tid] = w_out[(tid & 15) * 16 + (tid >> 4)];
    __syncthreads();

    const int rloc = tid >> 4;
    const int o = tid & 15;
    float acc = b_out[o];
    #pragma unroll
    for (int e = 0; e < 16; ++e)
        acc = fmaf(sx[rloc * 16 + e], sw[e * 16 + o], acc);
    out[gbase + tid] = acc;
}

// ---------------------------------------------------------------------------
extern "C" void kernel_launch(void* const* d_in, const int* in_sizes, int n_in,
                              void* d_out, int out_size, void* d_ws, size_t ws_size,
                              hipStream_t stream) {
    const float* board = (const float*)d_in[0];
    const float* w1    = (const float*)d_in[1];
    const float* b1    = (const float*)d_in[2];
    const float* w2    = (const float*)d_in[3];
    const float* b2    = (const float*)d_in[4];
    const float* w_qkv = (const float*)d_in[5];
    const float* b_qkv = (const float*)d_in[6];
    const float* w_out = (const float*)d_in[7];
    const float* b_out = (const float*)d_in[8];
    float* out = (float*)d_out;

    float* ws  = (float*)d_ws;
    float* Q   = ws;                        // (B,H,L,HD)
    float* K   = ws + (size_t)Rr * Ee;
    float* V   = ws + (size_t)2 * Rr * Ee;
    float* ATT = ws + (size_t)3 * Rr * Ee;  // (B,L,E)

    hipLaunchKernelGGL(enc_qkv_kernel, dim3(Rr / 64), dim3(256), 0, stream,
                       board, w1, b1, w2, b2, w_qkv, b_qkv, Q, K, V);
    hipLaunchKernelGGL(attn_kernel, dim3(Bn * Hh, 2), dim3(256), 0, stream,
                       Q, K, V, ATT);
    hipLaunchKernelGGL(outproj_kernel, dim3((Rr * Ee) / 256), dim3(256), 0, stream,
                       ATT, w_out, b_out, out);
}